// Round 2
// baseline (276.441 us; speedup 1.0000x reference)
//
#include <hip/hip_runtime.h>

// Shapes (fixed by the problem)
#define NB 4
#define LL 2048
#define SS 2048
#define HH 16
#define EE 64
#define DD 64

#define NHEAD (2*NB*HH)                       // 128 (st,n,h) heads
#define NCHUNK 8
#define KVP ((size_t)NHEAD*NCHUNK*4096)       // per-chunk partial KVT tiles
#define WSFLOATS (KVP + (size_t)NHEAD*NCHUNK*64)

typedef short short8 __attribute__((ext_vector_type(8)));
typedef float floatx4 __attribute__((ext_vector_type(4)));

__device__ inline float phi(float x) { return x > 0.f ? x + 1.f : __expf(x); }

// fp32 -> bf16 (RNE), result in low 16 bits
__device__ inline unsigned int f2bf(float f) {
    unsigned int x = __float_as_uint(f);
    return (x + 0x7FFFu + ((x >> 16) & 1u)) >> 16;
}
// split x into hi=bf16(x), lo=bf16(x-hi); pack pairs (a,b) -> (hi-pair, lo-pair)
__device__ inline void split_pack(float a, float b, unsigned int &hp, unsigned int &lp) {
    const unsigned int ha = f2bf(a), hb = f2bf(b);
    const float ra = a - __uint_as_float(ha << 16);
    const float rb = b - __uint_as_float(hb << 16);
    hp = (ha & 0xFFFFu) | (hb << 16);
    lp = (f2bf(ra) & 0xFFFFu) | (f2bf(rb) << 16);
}

// 16B-block XOR swizzle within an unpadded 64-short row.
// Writes (rows 4*d4+j): banks spread 2-way (free). Reads (b128, rows 16w+c):
// block' = (4ks+q) ^ f(row) stays bank-uniform. f(row) = ((row>>2)^row)&7.
__device__ inline int swz(int row, int col) {
    return ((((col >> 3) ^ ((row >> 2) ^ row)) & 7) << 3) | (col & 7);
}

// ---------------- Phase 1 (split-bf16 MFMA): KVT[m][d] = sum_s V[s,m]*phiK[s,d]*kl[s] --
// grid: 1024 = st(2)*n(4)*h(16)*schunk(8); block 256 (4 waves); 4 groups of 64 s.
// Writes per-chunk partial tiles (no atomics, no memset needed).
__global__ __launch_bounds__(256) void kv_kernel(
    const float* __restrict__ k1, const float* __restrict__ v1,
    const float* __restrict__ k2, const float* __restrict__ v2,
    const float* __restrict__ kl1, const float* __restrict__ kl2,
    float* __restrict__ ws)
{
    const int b = blockIdx.x;
    const int chunk = b & 7;
    const int h = (b >> 3) & 15;
    const int n = (b >> 7) & 3;
    const int st = (b >> 9) & 1;
    const float* K  = st ? k1 : k2;   // stream0 output attends K2/V2
    const float* V  = st ? v1 : v2;
    const float* KL = st ? kl1 : kl2;

    // Transposed bf16 tiles [row][s], unpadded 64-wide, XOR-swizzled (see swz).
    __shared__ __align__(16) unsigned short KtH[64][64];
    __shared__ __align__(16) unsigned short KtL[64][64];
    __shared__ __align__(16) unsigned short VtH[64][64];
    __shared__ __align__(16) unsigned short VtL[64][64];  // overlaid by scr at the end

    const int t = threadIdx.x;
    const int lane = t & 63;
    const int w = t >> 6;          // wave id: owns m-strip [16w,16w+16)
    const int d4 = t & 15;         // staging: column quad
    const int sp = t >> 4;         // staging: s-pair index 0..15
    const int c = lane & 15;
    const int q = lane >> 4;

    float ksum[4] = {0.f, 0.f, 0.f, 0.f};
    floatx4 acc[4];
#pragma unroll
    for (int i = 0; i < 4; i++) acc[i] = (floatx4){0.f, 0.f, 0.f, 0.f};

    // ---- register prefetch: group g's K/V/kl live in regs one iteration early ----
    float4 cur[8]; float curl[4];
    {
        const int sbase = chunk * 256;
#pragma unroll
        for (int i = 0; i < 2; ++i) {
            const int sl = 2 * sp + 32 * i;
            const size_t off = ((size_t)((size_t)n * SS + sbase + sl) * HH + h) * EE + 4 * d4;
            cur[4 * i + 0] = *(const float4*)&K[off];
            cur[4 * i + 1] = *(const float4*)&K[off + HH * EE];
            cur[4 * i + 2] = *(const float4*)&V[off];
            cur[4 * i + 3] = *(const float4*)&V[off + HH * EE];
            curl[2 * i + 0] = KL[(size_t)n * SS + sbase + sl];
            curl[2 * i + 1] = KL[(size_t)n * SS + sbase + sl + 1];
        }
    }

    for (int g = 0; g < 4; ++g) {
        float4 nxt[8]; float nxtl[4];
        if (g < 3) {
            const int sbase = chunk * 256 + (g + 1) * 64;
#pragma unroll
            for (int i = 0; i < 2; ++i) {
                const int sl = 2 * sp + 32 * i;
                const size_t off = ((size_t)((size_t)n * SS + sbase + sl) * HH + h) * EE + 4 * d4;
                nxt[4 * i + 0] = *(const float4*)&K[off];
                nxt[4 * i + 1] = *(const float4*)&K[off + HH * EE];
                nxt[4 * i + 2] = *(const float4*)&V[off];
                nxt[4 * i + 3] = *(const float4*)&V[off + HH * EE];
                nxtl[2 * i + 0] = KL[(size_t)n * SS + sbase + sl];
                nxtl[2 * i + 1] = KL[(size_t)n * SS + sbase + sl + 1];
            }
        }
        if (g) __syncthreads();   // tiles of group g-1 fully consumed before overwrite
        // ---- stage group g from registers: phi, keylen, hi/lo split, swizzled write ----
#pragma unroll
        for (int i = 0; i < 2; ++i) {
            const int sl = 2 * sp + 32 * i;
            const float4 ka = cur[4 * i + 0], kb = cur[4 * i + 1];
            const float4 va = cur[4 * i + 2], vb = cur[4 * i + 3];
            const float l0 = curl[2 * i + 0], l1 = curl[2 * i + 1];
            const float a0 = phi(ka.x) * l0, a1 = phi(ka.y) * l0;
            const float a2 = phi(ka.z) * l0, a3 = phi(ka.w) * l0;
            const float b0 = phi(kb.x) * l1, b1 = phi(kb.y) * l1;
            const float b2 = phi(kb.z) * l1, b3 = phi(kb.w) * l1;
            ksum[0] += a0 + b0; ksum[1] += a1 + b1;
            ksum[2] += a2 + b2; ksum[3] += a3 + b3;
            unsigned int hp, lp;
            const int r0 = 4 * d4;
            const int s0 = swz(r0 + 0, sl), s1 = swz(r0 + 1, sl);
            const int s2 = swz(r0 + 2, sl), s3 = swz(r0 + 3, sl);
            split_pack(a0, b0, hp, lp);
            *(unsigned int*)&KtH[r0 + 0][s0] = hp; *(unsigned int*)&KtL[r0 + 0][s0] = lp;
            split_pack(a1, b1, hp, lp);
            *(unsigned int*)&KtH[r0 + 1][s1] = hp; *(unsigned int*)&KtL[r0 + 1][s1] = lp;
            split_pack(a2, b2, hp, lp);
            *(unsigned int*)&KtH[r0 + 2][s2] = hp; *(unsigned int*)&KtL[r0 + 2][s2] = lp;
            split_pack(a3, b3, hp, lp);
            *(unsigned int*)&KtH[r0 + 3][s3] = hp; *(unsigned int*)&KtL[r0 + 3][s3] = lp;
            split_pack(va.x, vb.x, hp, lp);
            *(unsigned int*)&VtH[r0 + 0][s0] = hp; *(unsigned int*)&VtL[r0 + 0][s0] = lp;
            split_pack(va.y, vb.y, hp, lp);
            *(unsigned int*)&VtH[r0 + 1][s1] = hp; *(unsigned int*)&VtL[r0 + 1][s1] = lp;
            split_pack(va.z, vb.z, hp, lp);
            *(unsigned int*)&VtH[r0 + 2][s2] = hp; *(unsigned int*)&VtL[r0 + 2][s2] = lp;
            split_pack(va.w, vb.w, hp, lp);
            *(unsigned int*)&VtH[r0 + 3][s3] = hp; *(unsigned int*)&VtL[r0 + 3][s3] = lp;
        }
        __syncthreads();
        // ---- 3-term split MFMA: Vh*Kh + Vh*Kl + Vl*Kh ----
        const int ra = 16 * w + c;
#pragma unroll
        for (int ks = 0; ks < 2; ++ks) {
            const int ca = swz(ra, 32 * ks + 8 * q);
            const short8 aH = *(const short8*)&VtH[ra][ca];
            const short8 aL = *(const short8*)&VtL[ra][ca];
#pragma unroll
            for (int dt = 0; dt < 4; ++dt) {
                const int rb = 16 * dt + c;
                const int cb = swz(rb, 32 * ks + 8 * q);
                const short8 bH = *(const short8*)&KtH[rb][cb];
                const short8 bL = *(const short8*)&KtL[rb][cb];
                acc[dt] = __builtin_amdgcn_mfma_f32_16x16x32_bf16(aH, bH, acc[dt], 0, 0, 0);
                acc[dt] = __builtin_amdgcn_mfma_f32_16x16x32_bf16(aH, bL, acc[dt], 0, 0, 0);
                acc[dt] = __builtin_amdgcn_mfma_f32_16x16x32_bf16(aL, bH, acc[dt], 0, 0, 0);
            }
        }
        if (g < 3) {
#pragma unroll
            for (int i = 0; i < 8; ++i) cur[i] = nxt[i];
#pragma unroll
            for (int i = 0; i < 4; ++i) curl[i] = nxtl[i];
        }
    }

    // ---- store per-chunk partial KVT (plain stores): elem (m=16w+4q+r, d=16dt+c) ----
    const int head = (st * NB + n) * HH + h;
    const size_t kvbase = ((size_t)head * NCHUNK + chunk) * 4096;
#pragma unroll
    for (int dt = 0; dt < 4; ++dt)
#pragma unroll
        for (int r = 0; r < 4; ++r)
            ws[kvbase + (size_t)(16 * w + 4 * q + r) * 64 + 16 * dt + c] = acc[dt][r];

    // ---- Ksum partial (fp32, exact): reduce per-thread partials; scr overlays VtL ----
    float (*scr)[64] = (float(*)[64])VtL;   // 4 KB of the 8 KB tile
    __syncthreads();                        // last MFMA reads of VtL complete
    scr[sp][4 * d4 + 0] = ksum[0];
    scr[sp][4 * d4 + 1] = ksum[1];
    scr[sp][4 * d4 + 2] = ksum[2];
    scr[sp][4 * d4 + 3] = ksum[3];
    __syncthreads();
    if (t < 64) {
        float s = 0.f;
#pragma unroll
        for (int i = 0; i < 16; ++i) s += scr[i][t];
        ws[KVP + ((size_t)head * NCHUNK + chunk) * 64 + t] = s;
    }
}

// ---------------- Phase 2 (split-bf16 MFMA): out[l][m] = (phiQ[l]·KVT[m]) * Z[l] -------
// grid: 2048 = st(2)*n(4)*h(16)*lchunk(16, 128 rows each); block 256 (4 waves)
// Stages KVT by summing the 8 per-chunk partials; Z fused into the MFMA A-fragment pass.
static __device__ __forceinline__ float lt_body(
    const float4 qa0, const float4 qb0, const float4 qa1, const float4 qb1,
    const float* Ksp,
    const unsigned short (*BH)[72], const unsigned short (*BL)[72],
    const int c, const int q, floatx4* acc)
{
    float z = 0.f;
#pragma unroll
    for (int ks = 0; ks < 2; ++ks) {
        const float4 qa = ks ? qa1 : qa0;
        const float4 qb = ks ? qb1 : qb0;
        const int co = 32 * ks + 8 * q;
        const float p[8] = {phi(qa.x), phi(qa.y), phi(qa.z), phi(qa.w),
                            phi(qb.x), phi(qb.y), phi(qb.z), phi(qb.w)};
        z += p[0] * Ksp[co + 0] + p[1] * Ksp[co + 1]
           + p[2] * Ksp[co + 2] + p[3] * Ksp[co + 3]
           + p[4] * Ksp[co + 4] + p[5] * Ksp[co + 5]
           + p[6] * Ksp[co + 6] + p[7] * Ksp[co + 7];
        short8 aH, aL;
#pragma unroll
        for (int j = 0; j < 8; ++j) {
            const unsigned int hb = f2bf(p[j]);
            aH[j] = (short)hb;
            aL[j] = (short)f2bf(p[j] - __uint_as_float(hb << 16));
        }
#pragma unroll
        for (int mt = 0; mt < 4; ++mt) {
            const short8 bH = *(const short8*)&BH[16 * mt + c][co];
            const short8 bL = *(const short8*)&BL[16 * mt + c][co];
            acc[mt] = __builtin_amdgcn_mfma_f32_16x16x32_bf16(aH, bH, acc[mt], 0, 0, 0);
            acc[mt] = __builtin_amdgcn_mfma_f32_16x16x32_bf16(aH, bL, acc[mt], 0, 0, 0);
            acc[mt] = __builtin_amdgcn_mfma_f32_16x16x32_bf16(aL, bH, acc[mt], 0, 0, 0);
        }
    }
    return z;
}

__global__ __launch_bounds__(256) void out_kernel(
    const float* __restrict__ q1, const float* __restrict__ q2,
    const float* __restrict__ ws, float* __restrict__ out)
{
    const int b = blockIdx.x;
    const int lc = b & 15;
    const int h = (b >> 4) & 15;
    const int n = (b >> 8) & 3;
    const int st = (b >> 10) & 1;
    const float* Q = st ? q2 : q1;
    float* O = out + (size_t)st * ((size_t)NB * LL * HH * DD);

    __shared__ __align__(16) unsigned short BtH[64][72];  // KVT[m][d] hi
    __shared__ __align__(16) unsigned short BtL[64][72];  // KVT[m][d] lo
    __shared__ float Ks[64];

    const int t = threadIdx.x;
    const int lane = t & 63;
    const int w = t >> 6;          // wave: l-strip [32w, 32w+32)
    const int c = lane & 15;
    const int q = lane >> 4;
    const int head = (st * NB + n) * HH + h;
    const size_t kvb8 = (size_t)head * NCHUNK * 4096;
    const int lbase = lc * 128;

    // ---- prefetch Q (lt=0) BEFORE staging: HBM latency overlaps KVT staging+barrier ----
    const float* qr0 = &Q[((size_t)((size_t)n * LL + lbase + 32 * w + c) * HH + h) * EE];
    const int d0q = 8 * q;
    const float4 p00 = *(const float4*)&qr0[d0q];
    const float4 p01 = *(const float4*)&qr0[d0q + 4];
    const float4 p02 = *(const float4*)&qr0[d0q + 32];
    const float4 p03 = *(const float4*)&qr0[d0q + 36];

    // ---- stage KVT (sum of 8 chunk partials) -> hi/lo bf16 LDS ----
    {
        const int m = t >> 2;
        const int dbase = (t & 3) * 16;
#pragma unroll
        for (int i = 0; i < 4; ++i) {
            const int d0 = dbase + 4 * i;
            const size_t eo = (size_t)m * 64 + d0;
            float4 kv = *(const float4*)&ws[kvb8 + eo];
#pragma unroll
            for (int ch = 1; ch < NCHUNK; ++ch) {
                const float4 p = *(const float4*)&ws[kvb8 + (size_t)ch * 4096 + eo];
                kv.x += p.x; kv.y += p.y; kv.z += p.z; kv.w += p.w;
            }
            unsigned int hp, lp;
            split_pack(kv.x, kv.y, hp, lp);
            *(unsigned int*)&BtH[m][d0]     = hp; *(unsigned int*)&BtL[m][d0]     = lp;
            split_pack(kv.z, kv.w, hp, lp);
            *(unsigned int*)&BtH[m][d0 + 2] = hp; *(unsigned int*)&BtL[m][d0 + 2] = lp;
        }
    }
    if (t < 64) {
        float s = 0.f;
#pragma unroll
        for (int ch = 0; ch < NCHUNK; ++ch)
            s += ws[KVP + ((size_t)head * NCHUNK + ch) * 64 + t];
        Ks[t] = s;
    }
    __syncthreads();

    floatx4 acc[8];
#pragma unroll
    for (int i = 0; i < 8; ++i) acc[i] = (floatx4){0.f, 0.f, 0.f, 0.f};

    // ---- lt=0 (rows 32w .. 32w+15) ----
    float z0 = lt_body(p00, p01, p02, p03, Ks, BtH, BtL, c, q, acc);

    // ---- lt=1 (rows 32w+16 .. 32w+31); loads independent of body0, scheduler hoists ----
    const float* qr1 = qr0 + (size_t)16 * HH * EE;
    const float4 p10 = *(const float4*)&qr1[d0q];
    const float4 p11 = *(const float4*)&qr1[d0q + 4];
    const float4 p12 = *(const float4*)&qr1[d0q + 32];
    const float4 p13 = *(const float4*)&qr1[d0q + 36];
    float z1 = lt_body(p10, p11, p12, p13, Ks, BtH, BtL, c, q, acc + 4);

    // ---- complete Z row-sums across the 4 q-groups (same c = same row) ----
    z0 += __shfl_xor(z0, 16); z0 += __shfl_xor(z0, 32);
    z1 += __shfl_xor(z1, 16); z1 += __shfl_xor(z1, 32);
    const float zi0 = 1.f / (z0 + 1e-6f);   // lane (q,c) holds Z for row 32w+c
    const float zi1 = 1.f / (z1 + 1e-6f);   // lane (q,c) holds Z for row 32w+16+c

    // ---- epilogue: out element (l = 32w+16lt+4q+r, m = 16mt+c); Z via lane shuffle ----
#pragma unroll
    for (int lt = 0; lt < 2; ++lt) {
        const float zi = lt ? zi1 : zi0;
#pragma unroll
        for (int r = 0; r < 4; ++r) {
            const float zz = __shfl(zi, 4 * q + r);   // src lane c' = 4q+r holds row's Z
            const int ll = 32 * w + 16 * lt + 4 * q + r;
            const size_t ro = ((size_t)((size_t)n * LL + lbase + ll) * HH + h) * DD;
#pragma unroll
            for (int mt = 0; mt < 4; ++mt)
                O[ro + 16 * mt + c] = acc[4 * lt + mt][r] * zz;
        }
    }
}

extern "C" void kernel_launch(void* const* d_in, const int* in_sizes, int n_in,
                              void* d_out, int out_size, void* d_ws, size_t ws_size,
                              hipStream_t stream) {
    const float* q1  = (const float*)d_in[0];
    const float* k1  = (const float*)d_in[1];
    const float* v1  = (const float*)d_in[2];
    const float* q2  = (const float*)d_in[3];
    const float* k2  = (const float*)d_in[4];
    const float* v2  = (const float*)d_in[5];
    const float* kl1 = (const float*)d_in[6];
    const float* kl2 = (const float*)d_in[7];
    float* ws = (float*)d_ws;
    float* out = (float*)d_out;

    // No memset needed: kv_kernel fully overwrites its partial tiles (plain stores).
    kv_kernel<<<dim3(1024), dim3(256), 0, stream>>>(k1, v1, k2, v2, kl1, kl2, ws);
    out_kernel<<<dim3(2048), dim3(256), 0, stream>>>(q1, q2, ws, out);
}

// Round 4
// 240.832 us; speedup vs baseline: 1.1479x; 1.1479x over previous
//
#include <hip/hip_runtime.h>

// Shapes (fixed by the problem)
#define NB 4
#define LL 2048
#define SS 2048
#define HH 16
#define EE 64
#define DD 64

#define NHEAD (2*NB*HH)                       // 128 (st,n,h) heads
#define NCHUNK 8
#define KVP ((size_t)NHEAD*NCHUNK*4096)       // per-chunk partial KVT tiles
#define WSFLOATS (KVP + (size_t)NHEAD*NCHUNK*64)

typedef short short8 __attribute__((ext_vector_type(8)));
typedef float floatx4 __attribute__((ext_vector_type(4)));

__device__ inline float phi(float x) { return x > 0.f ? x + 1.f : __expf(x); }

// fp32 -> bf16 (RNE), result in low 16 bits
__device__ inline unsigned int f2bf(float f) {
    unsigned int x = __float_as_uint(f);
    return (x + 0x7FFFu + ((x >> 16) & 1u)) >> 16;
}
// split x into hi=bf16(x), lo=bf16(x-hi); pack pairs (a,b) -> (hi-pair, lo-pair)
__device__ inline void split_pack(float a, float b, unsigned int &hp, unsigned int &lp) {
    const unsigned int ha = f2bf(a), hb = f2bf(b);
    const float ra = a - __uint_as_float(ha << 16);
    const float rb = b - __uint_as_float(hb << 16);
    hp = (ha & 0xFFFFu) | (hb << 16);
    lp = (f2bf(ra) & 0xFFFFu) | (f2bf(rb) << 16);
}

// 16B-block XOR swizzle within an unpadded 64-short row.
// Writes (rows 4*d4+j): banks spread 2-way (free). Reads (b128, rows 16*x+c):
// slot = (4ks+q) ^ f(row) -> 8 lanes per 16B slot = bank minimum.
__device__ inline int swz(int row, int col) {
    return ((((col >> 3) ^ ((row >> 2) ^ row)) & 7) << 3) | (col & 7);
}

// ---------------- Phase 1 (split-bf16 MFMA): KVT[m][d] = sum_s V[s,m]*phiK[s,d]*kl[s] --
// grid: 1024 = st(2)*n(4)*h(16)*schunk(8); block 256 (4 waves); 4 groups of 64 s.
// Writes per-chunk partial tiles (no atomics, no memset needed).
__global__ __launch_bounds__(256) void kv_kernel(
    const float* __restrict__ k1, const float* __restrict__ v1,
    const float* __restrict__ k2, const float* __restrict__ v2,
    const float* __restrict__ kl1, const float* __restrict__ kl2,
    float* __restrict__ ws)
{
    const int b = blockIdx.x;
    const int chunk = b & 7;
    const int h = (b >> 3) & 15;
    const int n = (b >> 7) & 3;
    const int st = (b >> 9) & 1;
    const float* K  = st ? k1 : k2;   // stream0 output attends K2/V2
    const float* V  = st ? v1 : v2;
    const float* KL = st ? kl1 : kl2;

    // Transposed bf16 tiles [row][s], unpadded 64-wide, XOR-swizzled (see swz).
    __shared__ __align__(16) unsigned short KtH[64][64];
    __shared__ __align__(16) unsigned short KtL[64][64];
    __shared__ __align__(16) unsigned short VtH[64][64];
    __shared__ __align__(16) unsigned short VtL[64][64];  // overlaid by scr at the end

    const int t = threadIdx.x;
    const int lane = t & 63;
    const int w = t >> 6;          // wave id: owns m-strip [16w,16w+16)
    const int d4 = t & 15;         // staging: column quad
    const int sp = t >> 4;         // staging: s-pair index 0..15
    const int c = lane & 15;
    const int q = lane >> 4;

    float ksum[4] = {0.f, 0.f, 0.f, 0.f};
    floatx4 acc[4];
#pragma unroll
    for (int i = 0; i < 4; i++) acc[i] = (floatx4){0.f, 0.f, 0.f, 0.f};

    // ---- register prefetch: group g's K/V/kl live in regs one iteration early ----
    float4 cur[8]; float curl[4];
    {
        const int sbase = chunk * 256;
#pragma unroll
        for (int i = 0; i < 2; ++i) {
            const int sl = 2 * sp + 32 * i;
            const size_t off = ((size_t)((size_t)n * SS + sbase + sl) * HH + h) * EE + 4 * d4;
            cur[4 * i + 0] = *(const float4*)&K[off];
            cur[4 * i + 1] = *(const float4*)&K[off + HH * EE];
            cur[4 * i + 2] = *(const float4*)&V[off];
            cur[4 * i + 3] = *(const float4*)&V[off + HH * EE];
            curl[2 * i + 0] = KL[(size_t)n * SS + sbase + sl];
            curl[2 * i + 1] = KL[(size_t)n * SS + sbase + sl + 1];
        }
    }

    for (int g = 0; g < 4; ++g) {
        float4 nxt[8]; float nxtl[4];
        if (g < 3) {
            const int sbase = chunk * 256 + (g + 1) * 64;
#pragma unroll
            for (int i = 0; i < 2; ++i) {
                const int sl = 2 * sp + 32 * i;
                const size_t off = ((size_t)((size_t)n * SS + sbase + sl) * HH + h) * EE + 4 * d4;
                nxt[4 * i + 0] = *(const float4*)&K[off];
                nxt[4 * i + 1] = *(const float4*)&K[off + HH * EE];
                nxt[4 * i + 2] = *(const float4*)&V[off];
                nxt[4 * i + 3] = *(const float4*)&V[off + HH * EE];
                nxtl[2 * i + 0] = KL[(size_t)n * SS + sbase + sl];
                nxtl[2 * i + 1] = KL[(size_t)n * SS + sbase + sl + 1];
            }
        }
        if (g) __syncthreads();   // tiles of group g-1 fully consumed before overwrite
        // ---- stage group g from registers: phi, keylen, hi/lo split, swizzled write ----
#pragma unroll
        for (int i = 0; i < 2; ++i) {
            const int sl = 2 * sp + 32 * i;
            const float4 ka = cur[4 * i + 0], kb = cur[4 * i + 1];
            const float4 va = cur[4 * i + 2], vb = cur[4 * i + 3];
            const float l0 = curl[2 * i + 0], l1 = curl[2 * i + 1];
            const float a0 = phi(ka.x) * l0, a1 = phi(ka.y) * l0;
            const float a2 = phi(ka.z) * l0, a3 = phi(ka.w) * l0;
            const float b0 = phi(kb.x) * l1, b1 = phi(kb.y) * l1;
            const float b2 = phi(kb.z) * l1, b3 = phi(kb.w) * l1;
            ksum[0] += a0 + b0; ksum[1] += a1 + b1;
            ksum[2] += a2 + b2; ksum[3] += a3 + b3;
            unsigned int hp, lp;
            const int r0 = 4 * d4;
            const int s0 = swz(r0 + 0, sl), s1 = swz(r0 + 1, sl);
            const int s2 = swz(r0 + 2, sl), s3 = swz(r0 + 3, sl);
            split_pack(a0, b0, hp, lp);
            *(unsigned int*)&KtH[r0 + 0][s0] = hp; *(unsigned int*)&KtL[r0 + 0][s0] = lp;
            split_pack(a1, b1, hp, lp);
            *(unsigned int*)&KtH[r0 + 1][s1] = hp; *(unsigned int*)&KtL[r0 + 1][s1] = lp;
            split_pack(a2, b2, hp, lp);
            *(unsigned int*)&KtH[r0 + 2][s2] = hp; *(unsigned int*)&KtL[r0 + 2][s2] = lp;
            split_pack(a3, b3, hp, lp);
            *(unsigned int*)&KtH[r0 + 3][s3] = hp; *(unsigned int*)&KtL[r0 + 3][s3] = lp;
            split_pack(va.x, vb.x, hp, lp);
            *(unsigned int*)&VtH[r0 + 0][s0] = hp; *(unsigned int*)&VtL[r0 + 0][s0] = lp;
            split_pack(va.y, vb.y, hp, lp);
            *(unsigned int*)&VtH[r0 + 1][s1] = hp; *(unsigned int*)&VtL[r0 + 1][s1] = lp;
            split_pack(va.z, vb.z, hp, lp);
            *(unsigned int*)&VtH[r0 + 2][s2] = hp; *(unsigned int*)&VtL[r0 + 2][s2] = lp;
            split_pack(va.w, vb.w, hp, lp);
            *(unsigned int*)&VtH[r0 + 3][s3] = hp; *(unsigned int*)&VtL[r0 + 3][s3] = lp;
        }
        __syncthreads();
        // ---- 3-term split MFMA: Vh*Kh + Vh*Kl + Vl*Kh ----
        const int ra = 16 * w + c;
#pragma unroll
        for (int ks = 0; ks < 2; ++ks) {
            const int ca = swz(ra, 32 * ks + 8 * q);
            const short8 aH = *(const short8*)&VtH[ra][ca];
            const short8 aL = *(const short8*)&VtL[ra][ca];
#pragma unroll
            for (int dt = 0; dt < 4; ++dt) {
                const int rb = 16 * dt + c;
                const int cb = swz(rb, 32 * ks + 8 * q);
                const short8 bH = *(const short8*)&KtH[rb][cb];
                const short8 bL = *(const short8*)&KtL[rb][cb];
                acc[dt] = __builtin_amdgcn_mfma_f32_16x16x32_bf16(aH, bH, acc[dt], 0, 0, 0);
                acc[dt] = __builtin_amdgcn_mfma_f32_16x16x32_bf16(aH, bL, acc[dt], 0, 0, 0);
                acc[dt] = __builtin_amdgcn_mfma_f32_16x16x32_bf16(aL, bH, acc[dt], 0, 0, 0);
            }
        }
        if (g < 3) {
#pragma unroll
            for (int i = 0; i < 8; ++i) cur[i] = nxt[i];
#pragma unroll
            for (int i = 0; i < 4; ++i) curl[i] = nxtl[i];
        }
    }

    // ---- store per-chunk partial KVT (plain stores): elem (m=16w+4q+r, d=16dt+c) ----
    const int head = (st * NB + n) * HH + h;
    const size_t kvbase = ((size_t)head * NCHUNK + chunk) * 4096;
#pragma unroll
    for (int dt = 0; dt < 4; ++dt)
#pragma unroll
        for (int r = 0; r < 4; ++r)
            ws[kvbase + (size_t)(16 * w + 4 * q + r) * 64 + 16 * dt + c] = acc[dt][r];

    // ---- Ksum partial (fp32, exact): reduce per-thread partials; scr overlays VtL ----
    float (*scr)[64] = (float(*)[64])VtL;   // 4 KB of the 8 KB tile
    __syncthreads();                        // last MFMA reads of VtL complete
    scr[sp][4 * d4 + 0] = ksum[0];
    scr[sp][4 * d4 + 1] = ksum[1];
    scr[sp][4 * d4 + 2] = ksum[2];
    scr[sp][4 * d4 + 3] = ksum[3];
    __syncthreads();
    if (t < 64) {
        float s = 0.f;
#pragma unroll
        for (int i = 0; i < 16; ++i) s += scr[i][t];
        ws[KVP + ((size_t)head * NCHUNK + chunk) * 64 + t] = s;
    }
}

// ---------------- Phase 1.5: reduce 8 chunk partials once per head ------------------
// grid 128 (one block per head), block 256. Sums partials, does the bf16 hi/lo split,
// and stores the PRE-SWIZZLED tiles into the (now dead) chunk-0 partial space:
//   words [0,2048)  = hi tile (swz layout), words [2048,4096) = lo tile.
// Final Ksum overwrites the chunk-0 Ksum partial slot.
__global__ __launch_bounds__(256) void reduce_kernel(float* __restrict__ ws)
{
    const int head = blockIdx.x;
    const int t = threadIdx.x;
    const size_t base = (size_t)head * (NCHUNK * 4096);
    const int m = t >> 2;
    const int dbase = (t & 3) * 16;

    float4 kv[4];
#pragma unroll
    for (int i = 0; i < 4; ++i) {
        const int d0 = dbase + 4 * i;
        const size_t eo = (size_t)m * 64 + d0;
        float4 s = *(const float4*)&ws[base + eo];
#pragma unroll
        for (int ch = 1; ch < NCHUNK; ++ch) {
            const float4 p = *(const float4*)&ws[base + (size_t)ch * 4096 + eo];
            s.x += p.x; s.y += p.y; s.z += p.z; s.w += p.w;
        }
        kv[i] = s;
    }
    float ks = 0.f;
    if (t < 64) {
#pragma unroll
        for (int ch = 0; ch < NCHUNK; ++ch)
            ks += ws[KVP + ((size_t)head * NCHUNK + ch) * 64 + t];
    }
    __syncthreads();   // every thread's reads of this head's partials are done

    const int fm = ((m >> 2) ^ m) & 7;
    unsigned int* W = (unsigned int*)&ws[base];
#pragma unroll
    for (int i = 0; i < 4; ++i) {
        const int d0 = dbase + 4 * i;
        const int bp = ((((d0 >> 3) ^ fm) & 7) << 2) + ((d0 & 4) >> 1); // word pos in row
        unsigned int hp, lp;
        split_pack(kv[i].x, kv[i].y, hp, lp);
        W[m * 32 + bp]     = hp;  W[2048 + m * 32 + bp]     = lp;
        split_pack(kv[i].z, kv[i].w, hp, lp);
        W[m * 32 + bp + 1] = hp;  W[2048 + m * 32 + bp + 1] = lp;
    }
    if (t < 64) ws[KVP + (size_t)head * NCHUNK * 64 + t] = ks;
}

// ---------------- Phase 2 (split-bf16 MFMA): out[l][m] = (phiQ[l]·KVT[m]) * Z[l] -------
// grid: 2048 = st(2)*n(4)*h(16)*lchunk(16, 128 rows each); block 256 (4 waves)
// Staging = flat uint4 memcpy of pre-swizzled bf16 tiles; Z fused in A-fragment pass.
static __device__ __forceinline__ float lt_body(
    const float4 qa0, const float4 qb0, const float4 qa1, const float4 qb1,
    const float* Ksp,
    const unsigned short (*BH)[64], const unsigned short (*BL)[64],
    const int c, const int q, floatx4* acc)
{
    float z = 0.f;
#pragma unroll
    for (int ks = 0; ks < 2; ++ks) {
        const float4 qa = ks ? qa1 : qa0;
        const float4 qb = ks ? qb1 : qb0;
        const int co = 32 * ks + 8 * q;
        const float p[8] = {phi(qa.x), phi(qa.y), phi(qa.z), phi(qa.w),
                            phi(qb.x), phi(qb.y), phi(qb.z), phi(qb.w)};
        z += p[0] * Ksp[co + 0] + p[1] * Ksp[co + 1]
           + p[2] * Ksp[co + 2] + p[3] * Ksp[co + 3]
           + p[4] * Ksp[co + 4] + p[5] * Ksp[co + 5]
           + p[6] * Ksp[co + 6] + p[7] * Ksp[co + 7];
        short8 aH, aL;
#pragma unroll
        for (int j = 0; j < 8; ++j) {
            const unsigned int hb = f2bf(p[j]);
            aH[j] = (short)hb;
            aL[j] = (short)f2bf(p[j] - __uint_as_float(hb << 16));
        }
#pragma unroll
        for (int mt = 0; mt < 4; ++mt) {
            const int rb = 16 * mt + c;
            const int cb = swz(rb, co);
            const short8 bH = *(const short8*)&BH[rb][cb];
            const short8 bL = *(const short8*)&BL[rb][cb];
            acc[mt] = __builtin_amdgcn_mfma_f32_16x16x32_bf16(aH, bH, acc[mt], 0, 0, 0);
            acc[mt] = __builtin_amdgcn_mfma_f32_16x16x32_bf16(aH, bL, acc[mt], 0, 0, 0);
            acc[mt] = __builtin_amdgcn_mfma_f32_16x16x32_bf16(aL, bH, acc[mt], 0, 0, 0);
        }
    }
    return z;
}

__global__ __launch_bounds__(256) void out_kernel(
    const float* __restrict__ q1, const float* __restrict__ q2,
    const float* __restrict__ ws, float* __restrict__ out)
{
    const int b = blockIdx.x;
    const int lc = b & 15;
    const int h = (b >> 4) & 15;
    const int n = (b >> 8) & 3;
    const int st = (b >> 10) & 1;
    const float* Q = st ? q2 : q1;
    float* O = out + (size_t)st * ((size_t)NB * LL * HH * DD);

    __shared__ __align__(16) unsigned short BtH[64][64];  // KVT[m][d] hi (swz layout)
    __shared__ __align__(16) unsigned short BtL[64][64];  // KVT[m][d] lo (swz layout)
    __shared__ float Ks[64];

    const int t = threadIdx.x;
    const int lane = t & 63;
    const int w = t >> 6;          // wave: l-strip [32w, 32w+32)
    const int c = lane & 15;
    const int q = lane >> 4;
    const int head = (st * NB + n) * HH + h;
    const int lbase = lc * 128;

    // ---- all Q loads issued BEFORE staging: HBM latency overlaps staging+barrier ----
    const float* qr0 = &Q[((size_t)((size_t)n * LL + lbase + 32 * w + c) * HH + h) * EE];
    const int d0q = 8 * q;
    const float4 p00 = *(const float4*)&qr0[d0q];
    const float4 p01 = *(const float4*)&qr0[d0q + 4];
    const float4 p02 = *(const float4*)&qr0[d0q + 32];
    const float4 p03 = *(const float4*)&qr0[d0q + 36];
    const float* qr1 = qr0 + (size_t)16 * HH * EE;
    const float4 p10 = *(const float4*)&qr1[d0q];
    const float4 p11 = *(const float4*)&qr1[d0q + 4];
    const float4 p12 = *(const float4*)&qr1[d0q + 32];
    const float4 p13 = *(const float4*)&qr1[d0q + 36];

    // ---- stage pre-split, pre-swizzled KVT tiles: flat 16 KB copy (1024 uint4) ----
    {
        const uint4* src = (const uint4*)(ws + (size_t)head * (NCHUNK * 4096));
        uint4* dstH = (uint4*)&BtH[0][0];   // hi tile: 8 KB = 512 uint4
        uint4* dstL = (uint4*)&BtL[0][0];   // lo tile: 8 KB = 512 uint4
        dstH[t]       = src[t];
        dstH[t + 256] = src[t + 256];
        dstL[t]       = src[512 + t];
        dstL[t + 256] = src[768 + t];
    }
    if (t < 64) Ks[t] = ws[KVP + (size_t)head * NCHUNK * 64 + t];
    __syncthreads();

    floatx4 acc[8];
#pragma unroll
    for (int i = 0; i < 8; ++i) acc[i] = (floatx4){0.f, 0.f, 0.f, 0.f};

    // ---- lt=0 (rows 32w .. 32w+15) ----
    float z0 = lt_body(p00, p01, p02, p03, Ks, BtH, BtL, c, q, acc);
    // ---- lt=1 (rows 32w+16 .. 32w+31) ----
    float z1 = lt_body(p10, p11, p12, p13, Ks, BtH, BtL, c, q, acc + 4);

    // ---- complete Z row-sums across the 4 q-groups (same c = same row) ----
    z0 += __shfl_xor(z0, 16); z0 += __shfl_xor(z0, 32);
    z1 += __shfl_xor(z1, 16); z1 += __shfl_xor(z1, 32);
    const float zi0 = 1.f / (z0 + 1e-6f);   // lane (q,c) holds Z for row 32w+c
    const float zi1 = 1.f / (z1 + 1e-6f);   // lane (q,c) holds Z for row 32w+16+c

    // ---- epilogue: out element (l = 32w+16lt+4q+r, m = 16mt+c); Z via lane shuffle ----
#pragma unroll
    for (int lt = 0; lt < 2; ++lt) {
        const float zi = lt ? zi1 : zi0;
#pragma unroll
        for (int r = 0; r < 4; ++r) {
            const float zz = __shfl(zi, 4 * q + r);   // src lane c' = 4q+r holds row's Z
            const int ll = 32 * w + 16 * lt + 4 * q + r;
            const size_t ro = ((size_t)((size_t)n * LL + lbase + ll) * HH + h) * DD;
#pragma unroll
            for (int mt = 0; mt < 4; ++mt)
                O[ro + 16 * mt + c] = acc[4 * lt + mt][r] * zz;
        }
    }
}

extern "C" void kernel_launch(void* const* d_in, const int* in_sizes, int n_in,
                              void* d_out, int out_size, void* d_ws, size_t ws_size,
                              hipStream_t stream) {
    const float* q1  = (const float*)d_in[0];
    const float* k1  = (const float*)d_in[1];
    const float* v1  = (const float*)d_in[2];
    const float* q2  = (const float*)d_in[3];
    const float* k2  = (const float*)d_in[4];
    const float* v2  = (const float*)d_in[5];
    const float* kl1 = (const float*)d_in[6];
    const float* kl2 = (const float*)d_in[7];
    float* ws = (float*)d_ws;
    float* out = (float*)d_out;

    // No memset needed: kv_kernel fully overwrites its partial tiles (plain stores).
    kv_kernel<<<dim3(1024), dim3(256), 0, stream>>>(k1, v1, k2, v2, kl1, kl2, ws);
    reduce_kernel<<<dim3(128), dim3(256), 0, stream>>>(ws);
    out_kernel<<<dim3(2048), dim3(256), 0, stream>>>(q1, q2, ws, out);
}